// Round 15
// baseline (92.650 us; speedup 1.0000x reference)
//
#include <hip/hip_runtime.h>
#include <hip/hip_bf16.h>

#define NN 4096
#define DD 768
#define CCL 97
#define KI 24                // 24 K-steps of K=32
#define FSCALE 16.0f         // fp8 pre-scale; sims = acc / (FSCALE^2 * TAU)

typedef __attribute__((ext_vector_type(2))) long i64x2;
typedef __attribute__((ext_vector_type(16))) float f32x16;
typedef unsigned long long u64;

// workspace layout (bytes)
#define SZ_FT    (NN*DD)                    // 3.1 MB fp8 fragment-tiled F (L2-resident)
#define OFF_R    (SZ_FT)
#define OFF_S    (OFF_R + NN*4)
#define OFF_C    (OFF_S + NN*4)
#define OFF_BITS (OFF_C + NN*4)             // 4096 * 16B
#define OFF_LM   (OFF_BITS + NN*16)         // 4096 f32

__device__ __forceinline__ ulonglong2 shfl_bits(ulonglong2 v, int src) {
  ulonglong2 r;
  r.x = __shfl((u64)v.x, src, 64);
  r.y = __shfl((u64)v.y, src, 64);
  return r;
}

__device__ __forceinline__ bool ovl(ulonglong2 a, ulonglong2 b) {
  return ((a.x & b.x) | (a.y & b.y)) != 0ULL;
}

// fused: blocks 0..1535 convert F -> fp8 tiles; blocks 1536..1599 pack label
// bits + label_mask + zero accumulators.
// fp8 layout: chunk(g32, kc32) = 1KB at (g32*24+kc32)*1024; lane (l31,h) slot =
// l31*32 + h*16; slot bytes [0,8)=k0..7 |[8,16)=k16..23 |[16,24)=k8..15 |[24,32)=k24..31
__global__ __launch_bounds__(256) void convert_prep_kernel(
    const float* __restrict__ F, char* __restrict__ Ft,
    const int* __restrict__ labels, ulonglong2* __restrict__ bits,
    float* __restrict__ lm, float* __restrict__ R, float* __restrict__ S,
    float* __restrict__ Cc) {
  const int b = blockIdx.x;
  if (b < 1536) {
    int idx = b * 256 + threadIdx.x;               // 0 .. NN*96-1 (8 f32/thread)
    int r = idx / 96, kc = idx - r * 96;           // kc = which 8-k group
    const float* src = F + (long)r * DD + kc * 8;
    float f[8];
#pragma unroll
    for (int j = 0; j < 8; ++j) f[j] = src[j] * FSCALE;
    int lo = __builtin_amdgcn_cvt_pk_fp8_f32(f[0], f[1], 0, false);
    lo = __builtin_amdgcn_cvt_pk_fp8_f32(f[2], f[3], lo, true);
    int hi = __builtin_amdgcn_cvt_pk_fp8_f32(f[4], f[5], 0, false);
    hi = __builtin_amdgcn_cvt_pk_fp8_f32(f[6], f[7], hi, true);
    int g32 = r >> 5, l31 = r & 31;
    int ks32 = kc >> 2, k8 = kc & 3;               // k = ks32*32 + k8*8
    int hp = k8 & 1, m = k8 >> 1;
    long off = (long)(g32 * 24 + ks32) * 1024 + l31 * 32 + hp * 16 + m * 8;
    *((int2*)(Ft + off)) = make_int2(lo, hi);
  } else {
    const int wave = threadIdx.x >> 6, lane = threadIdx.x & 63;
    const int base = (b - 1536) * 64 + wave * 16;
#pragma unroll
    for (int it = 0; it < 16; ++it) {
      int gw = base + it;
      const int* lr = labels + (long)gw * CCL;
      int v0 = lr[lane];
      int c1 = 64 + lane;
      int v1 = (c1 < CCL) ? lr[c1] : 0;
      u64 m0 = __ballot(v0 == 1);
      u64 m1 = __ballot(v1 == 1);
      if (lane == 0) {
        bits[gw] = make_ulonglong2(m0, m1);
        lm[gw] = (lr[0] != 1) ? 1.0f : 0.0f;
        R[gw] = 0.f; S[gw] = 0.f; Cc[gw] = 0.f;
      }
    }
  }
}

__device__ __forceinline__ int tri_base(int i) {
  int k = i >> 1;
  return 64 * i - ((i & 1) ? k * k : k * (k - 1));
}

// straddle-triangle: one 32x64 tile per wave; tile t -> (i: 32-row panel 0..127,
// j: 64-col panel, j >= i>>1); 4160 tiles, 1040 blocks x 4 independent waves;
// no LDS, no barriers; ring-3 global prefetch (R8 body). Each kept element
// (c > r in straddle tiles, all in off-diag tiles) feeds row r stats AND
// (symmetric) col c stats.
__global__ __launch_bounds__(256, 4) void main_kernel(
    const char* __restrict__ Ft, const ulonglong2* __restrict__ bits,
    float* __restrict__ R, float* __restrict__ S, float* __restrict__ Cc) {
  const int lane = threadIdx.x & 63;
  const int wave = threadIdx.x >> 6;
  const int l31 = lane & 31, h = lane >> 5;

  // XCD swizzle on blocks (1040 = 8*130, bijective)
  int b0 = blockIdx.x;
  int nb = (b0 & 7) * 130 + (b0 >> 3);
  int t = nb * 4 + wave;                   // 0..4159
  // decode i: base(i) = 64i - S(i); i ~ 2*(64 - sqrt(4096 - t))
  int i = (int)(2.0f * (64.0f - sqrtf(fmaxf(4096.0f - (float)t, 0.0f))));
  if (i > 127) i = 127;
  if (i < 0) i = 0;
  while (i < 127 && tri_base(i + 1) <= t) ++i;
  while (i > 0 && tri_base(i) > t) --i;
  const int j = (i >> 1) + (t - tri_base(i));
  const bool straddle = (j == (i >> 1));
  const int Rr = 32 * i;                   // row base (B operand, 32 rows)
  const int Cb = 64 * j;                   // col base (A operand, 64 cols)

  const int laddr = l31 * 32 + h * 16;
  const char* pa0 = Ft + (long)((2 * j) * KI) * 1024 + laddr;      // cols 0-31
  const char* pa1 = Ft + (long)((2 * j + 1) * KI) * 1024 + laddr;  // cols 32-63
  const char* pb  = Ft + (long)(i * KI) * 1024 + laddr;            // rows

  f32x16 acc0 = (f32x16)(0.f);             // cols Cb+0..31
  f32x16 acc1 = (f32x16)(0.f);             // cols Cb+32..63

#define LOADS(V, it) do {                               \
    V##A0 = *(const i64x2*)(pa0 + (it) * 1024);         \
    V##A1 = *(const i64x2*)(pa1 + (it) * 1024);         \
    V##B  = *(const i64x2*)(pb  + (it) * 1024);         \
  } while (0)
#define MM(V) do {                                                              \
    acc0 = __builtin_amdgcn_mfma_f32_32x32x16_fp8_fp8(V##A0.x, V##B.x, acc0, 0, 0, 0); \
    acc1 = __builtin_amdgcn_mfma_f32_32x32x16_fp8_fp8(V##A1.x, V##B.x, acc1, 0, 0, 0); \
    acc0 = __builtin_amdgcn_mfma_f32_32x32x16_fp8_fp8(V##A0.y, V##B.y, acc0, 0, 0, 0); \
    acc1 = __builtin_amdgcn_mfma_f32_32x32x16_fp8_fp8(V##A1.y, V##B.y, acc1, 0, 0, 0); \
  } while (0)

  i64x2 xA0, xA1, xB, yA0, yA1, yB, zA0, zA1, zB;   // ring-3 (9 loads in flight)
  LOADS(x, 0); LOADS(y, 1); LOADS(z, 2);
#pragma unroll
  for (int it = 0; it < KI; it += 3) {
    MM(x);
    if (it + 3 < KI) LOADS(x, it + 3);
    MM(y);
    if (it + 4 < KI) LOADS(y, it + 4);
    MM(z);
    if (it + 5 < KI) LOADS(z, it + 5);
  }
#undef LOADS
#undef MM

  // ---- epilogue: both roles ----
  // sims[row = Rr + l31][col = Cb + cj*32 + crow(reg,h)], crow=(reg&3)+8*(reg>>2)+4*h
  const float sscale = 1.0f / (FSCALE * FSCALE * 2.0f);   // includes /TAU
  const int r = Rr + l31;
  const ulonglong2 rb = bits[r];
  const ulonglong2 cbl0 = bits[Cb + l31];        // col bits, cj=0, lane-indexed
  const ulonglong2 cbl1 = bits[Cb + 32 + l31];   // col bits, cj=1

  float rs = 0.f, ss = 0.f, cs = 0.f;
#pragma unroll
  for (int reg = 0; reg < 16; ++reg) {
    const int crow = (reg & 3) + 8 * (reg >> 2) + 4 * h;
    const ulonglong2 cq0 = shfl_bits(cbl0, crow);   // bits[Cb + crow]
    const ulonglong2 cq1 = shfl_bits(cbl1, crow);   // bits[Cb + 32 + crow]
    const int c0 = Cb + crow, c1 = Cb + 32 + crow;
    const float k0 = (!straddle || (c0 > r)) ? 1.f : 0.f;
    const float k1 = (!straddle || (c1 > r)) ? 1.f : 0.f;
    float v0 = acc0[reg] * sscale;
    float v1 = acc1[reg] * sscale;
    float e0 = __expf(v0) * k0;
    float e1 = __expf(v1) * k1;
    float o0 = ovl(rb, cq0) ? k0 : 0.f;
    float o1 = ovl(rb, cq1) ? k1 : 0.f;
    // row-role
    rs += e0 + e1;
    ss = fmaf(o0, v0, ss); ss = fmaf(o1, v1, ss);
    cs += o0 + o1;
    // col-role partials: reduce over the 32 rows (l31) within each half
    float ar0 = e0, av0 = o0 * v0, an0 = o0;
    float ar1 = e1, av1 = o1 * v1, an1 = o1;
#pragma unroll
    for (int d = 1; d < 32; d <<= 1) {
      ar0 += __shfl_xor(ar0, d, 32); av0 += __shfl_xor(av0, d, 32);
      an0 += __shfl_xor(an0, d, 32); ar1 += __shfl_xor(ar1, d, 32);
      av1 += __shfl_xor(av1, d, 32); an1 += __shfl_xor(an1, d, 32);
    }
    if (l31 == 0) {      // lanes 0 (h=0) and 32 (h=1): distinct crow -> distinct cols
      atomicAdd(R + c0, ar0); atomicAdd(S + c0, av0); atomicAdd(Cc + c0, an0);
      atomicAdd(R + c1, ar1); atomicAdd(S + c1, av1); atomicAdd(Cc + c1, an1);
    }
  }
  // row-role: combine halves (same rows, disjoint cols), one atomic set per row
  rs += __shfl_xor(rs, 32, 64);
  ss += __shfl_xor(ss, 32, 64);
  cs += __shfl_xor(cs, 32, 64);
  if (lane < 32) {
    atomicAdd(R + r, rs); atomicAdd(S + r, ss); atomicAdd(Cc + r, cs);
  }
}

__global__ __launch_bounds__(1024) void finalize_kernel(
    const float* __restrict__ R, const float* __restrict__ S,
    const float* __restrict__ Cc, const float* __restrict__ lm,
    float* __restrict__ out) {
  int tid = threadIdx.x;
  float s1 = 0.f, s2 = 0.f, slm = 0.f;
  for (int i = tid; i < NN; i += 1024) {
    float r = R[i], s = S[i], c = Cc[i], l = lm[i];
    float logR = __logf(r);
    float lp1 = (c > 0.f) ? (s - c * logR) / c : 0.f;
    // logits_max = sims_ii = 0.5 exactly (normalized rows, row max by C-S)
    float lp2 = (c == 0.f) ? (0.5f - logR) : 0.f;
    s1 += lp1 * l; s2 += lp2; slm += l;
  }
#pragma unroll
  for (int d = 1; d < 64; d <<= 1) {
    s1 += __shfl_xor(s1, d, 64);
    s2 += __shfl_xor(s2, d, 64);
    slm += __shfl_xor(slm, d, 64);
  }
  __shared__ float w1[16], w2[16], w3[16];
  int w = tid >> 6;
  if ((tid & 63) == 0) { w1[w] = s1; w2[w] = s2; w3[w] = slm; }
  __syncthreads();
  if (tid == 0) {
    float a = 0.f, b = 0.f, c2 = 0.f;
    for (int q = 0; q < 16; ++q) { a += w1[q]; b += w2[q]; c2 += w3[q]; }
    const float inv = 1.0f / (float)NN;
    out[0] = -2.0f * (a * inv + b * c2 * inv * inv);
  }
}

extern "C" void kernel_launch(void* const* d_in, const int* in_sizes, int n_in,
                              void* d_out, int out_size, void* d_ws, size_t ws_size,
                              hipStream_t stream) {
  const float* F = (const float*)d_in[0];
  const int* labels = (const int*)d_in[1];
  float* out = (float*)d_out;
  char* ws = (char*)d_ws;

  char* Ft = ws;
  float* R = (float*)(ws + OFF_R);
  float* S = (float*)(ws + OFF_S);
  float* Cc = (float*)(ws + OFF_C);
  ulonglong2* bits = (ulonglong2*)(ws + OFF_BITS);
  float* lm = (float*)(ws + OFF_LM);

  convert_prep_kernel<<<1600, 256, 0, stream>>>(F, Ft, labels, bits, lm, R, S, Cc);
  main_kernel<<<1040, 256, 0, stream>>>(Ft, bits, R, S, Cc);
  finalize_kernel<<<1, 1024, 0, stream>>>(R, S, Cc, lm, out);
}

// Round 16
// 44.943 us; speedup vs baseline: 2.0615x; 2.0615x over previous
//
#include <hip/hip_runtime.h>
#include <hip/hip_bf16.h>

#define NN 4096
#define DD 768
#define CCL 97
#define KI 24                // 24 K-steps of K=32
#define FSCALE 16.0f         // fp8 pre-scale; sims = acc / (FSCALE^2 * TAU)

typedef __attribute__((ext_vector_type(2))) long i64x2;
typedef __attribute__((ext_vector_type(16))) float f32x16;
typedef unsigned long long u64;

// workspace layout (bytes)
#define SZ_FT    (NN*DD)                    // 3.1 MB fp8 fragment-tiled F (L2-resident)
#define OFF_R    (SZ_FT)
#define OFF_S    (OFF_R + NN*4)
#define OFF_C    (OFF_S + NN*4)
#define OFF_BITS (OFF_C + NN*4)             // 4096 * 16B
#define OFF_LM   (OFF_BITS + NN*16)         // 4096 f32

__device__ __forceinline__ ulonglong2 shfl_bits(ulonglong2 v, int src) {
  ulonglong2 r;
  r.x = __shfl((u64)v.x, src, 64);
  r.y = __shfl((u64)v.y, src, 64);
  return r;
}

__device__ __forceinline__ bool ovl(ulonglong2 a, ulonglong2 b) {
  return ((a.x & b.x) | (a.y & b.y)) != 0ULL;
}

// one wave per row: pack 97 labels into 2x u64 via ballot; label_mask; zero accums
__global__ void prep_bits_kernel(const int* __restrict__ labels,
                                 ulonglong2* __restrict__ bits,
                                 float* __restrict__ lm,
                                 float* __restrict__ R, float* __restrict__ S,
                                 float* __restrict__ Cc) {
  int gw = (blockIdx.x * blockDim.x + threadIdx.x) >> 6;
  int lane = threadIdx.x & 63;
  if (gw >= NN) return;
  const int* lr = labels + (long)gw * CCL;
  int v0 = lr[lane];
  int c1 = 64 + lane;
  int v1 = (c1 < CCL) ? lr[c1] : 0;
  u64 m0 = __ballot(v0 == 1);
  u64 m1 = __ballot(v1 == 1);
  if (lane == 0) {
    bits[gw] = make_ulonglong2(m0, m1);
    lm[gw] = (lr[0] != 1) ? 1.0f : 0.0f;
    R[gw] = 0.f; S[gw] = 0.f; Cc[gw] = 0.f;
  }
}

// f32 [N][D] -> fp8 e4m3 (x FSCALE), tiled per 32-row group for 32x32x16 MFMA:
// chunk(g32, ks) = 1KB at (g32*KI+ks)*1024; lane (l31,h) slot = l31*32 + h*16;
// slot bytes: [0,8)=k0..7 | [8,16)=k16..23 | [16,24)=k8..15 | [24,32)=k24..31
__global__ void convert_kernel(const float* __restrict__ F, char* __restrict__ Ft) {
  int idx = blockIdx.x * 256 + threadIdx.x;      // 0 .. NN*96-1 (8 f32 per thread)
  int r = idx / 96, kc = idx - r * 96;           // kc = which 8-k group
  const float* src = F + (long)r * DD + kc * 8;
  float f[8];
#pragma unroll
  for (int j = 0; j < 8; ++j) f[j] = src[j] * FSCALE;
  int lo = __builtin_amdgcn_cvt_pk_fp8_f32(f[0], f[1], 0, false);
  lo = __builtin_amdgcn_cvt_pk_fp8_f32(f[2], f[3], lo, true);
  int hi = __builtin_amdgcn_cvt_pk_fp8_f32(f[4], f[5], 0, false);
  hi = __builtin_amdgcn_cvt_pk_fp8_f32(f[6], f[7], hi, true);
  int g32 = r >> 5, l31 = r & 31;
  int ks32 = kc >> 2, k8 = kc & 3;               // k = ks32*32 + k8*8
  int hp = k8 & 1, m = k8 >> 1;
  long off = (long)(g32 * KI + ks32) * 1024 + l31 * 32 + hp * 16 + m * 8;
  *((int2*)(Ft + off)) = make_int2(lo, hi);
}

__device__ __forceinline__ void gload_lds16(const char* gsrc, char* ldst) {
  __builtin_amdgcn_global_load_lds(
      (const __attribute__((address_space(1))) void*)gsrc,
      (__attribute__((address_space(3))) void*)ldst, 16, 0, 0);
}

#define WAITV(N) asm volatile("s_waitcnt vmcnt(" #N ")" ::: "memory")

// 128x128 block tile (4 waves x 64x64), panels staged once per block via
// global_load_lds; 3-buffer ring, ONE barrier + counted vmcnt per K-step;
// full square grid, 1024 blocks = 4/CU resident.
__global__ __launch_bounds__(256, 4) void main_kernel(
    const char* __restrict__ Ft, const ulonglong2* __restrict__ bits,
    float* __restrict__ R, float* __restrict__ S, float* __restrict__ Cc) {
  __shared__ char lds[3][8192];          // [buf][A 4KB | B 4KB]
  const int tid = threadIdx.x;
  const int wave = tid >> 6, lane = tid & 63;
  const int wi = wave >> 1, wj = wave & 1;
  const int l31 = lane & 31, h = lane >> 5;

  // XCD swizzle (1024 = 8*128, bijective); supertile (I,J) of 128x128
  int b0 = blockIdx.x;
  int nb = (b0 & 7) * 128 + (b0 >> 3);
  const int I = nb >> 5, J = nb & 31;
  const int ti = I * 2 + wi;             // wave's 64-row group (B operand)
  const int tj = J * 2 + wj;             // wave's 64-col group (A operand)
  const int R0 = ti * 64, C0 = tj * 64;
  const bool samegrp = (ti == tj);

  // staging: wave stages A chunk (group J*4+wave) and B chunk (group I*4+wave)
  const char* gsrcA = Ft + (long)((J * 4 + wave) * KI) * 1024 + lane * 16;
  const char* gsrcB = Ft + (long)((I * 4 + wave) * KI) * 1024 + lane * 16;

#define STAGE(ks, bi) do {                                     \
    gload_lds16(gsrcA + (ks) * 1024, &lds[bi][wave * 1024]);   \
    gload_lds16(gsrcB + (ks) * 1024, &lds[bi][4096 + wave * 1024]); \
  } while (0)

  f32x16 acc00, acc01, acc10, acc11;     // acc[cj][ri]
  acc00 = (f32x16)(0.f); acc01 = (f32x16)(0.f);
  acc10 = (f32x16)(0.f); acc11 = (f32x16)(0.f);

  STAGE(0, 0);
  STAGE(1, 1);

  const int offA0 = (2 * wj) * 1024 + lane * 16;
  const int offB0 = 4096 + (2 * wi) * 1024 + lane * 16;

  int buf = 0;
  for (int ks = 0; ks < KI; ++ks) {
    // steady state: outstanding = ks(2) + ks+1(2); drain ks only, keep ks+1 in flight
    if (ks < KI - 1) WAITV(2);
    else             WAITV(0);
    __builtin_amdgcn_s_barrier();        // all waves done reading buf (ks-1)%3
    asm volatile("" ::: "memory");       // no mem op crosses above the barrier
    if (ks + 2 < KI) {
      int nbf = buf + 2; if (nbf >= 3) nbf -= 3;
      STAGE(ks + 2, nbf);                // overwrites buf computed at ks-1: safe
    }
    const char* base = &lds[buf][0];
    i64x2 A0 = *(const i64x2*)(base + offA0);
    i64x2 A1 = *(const i64x2*)(base + offA0 + 1024);
    i64x2 B0 = *(const i64x2*)(base + offB0);
    i64x2 B1 = *(const i64x2*)(base + offB0 + 1024);
    acc00 = __builtin_amdgcn_mfma_f32_32x32x16_fp8_fp8(A0.x, B0.x, acc00, 0, 0, 0);
    acc01 = __builtin_amdgcn_mfma_f32_32x32x16_fp8_fp8(A0.x, B1.x, acc01, 0, 0, 0);
    acc10 = __builtin_amdgcn_mfma_f32_32x32x16_fp8_fp8(A1.x, B0.x, acc10, 0, 0, 0);
    acc11 = __builtin_amdgcn_mfma_f32_32x32x16_fp8_fp8(A1.x, B1.x, acc11, 0, 0, 0);
    acc00 = __builtin_amdgcn_mfma_f32_32x32x16_fp8_fp8(A0.y, B0.y, acc00, 0, 0, 0);
    acc01 = __builtin_amdgcn_mfma_f32_32x32x16_fp8_fp8(A0.y, B1.y, acc01, 0, 0, 0);
    acc10 = __builtin_amdgcn_mfma_f32_32x32x16_fp8_fp8(A1.y, B0.y, acc10, 0, 0, 0);
    acc11 = __builtin_amdgcn_mfma_f32_32x32x16_fp8_fp8(A1.y, B1.y, acc11, 0, 0, 0);
    buf = (buf == 2) ? 0 : buf + 1;
  }
#undef STAGE

  // ---- epilogue: row stats, bits-based overlap (L2-clean) ----
  // sims[row = R0 + ri*32 + l31][col = C0 + cj*32 + crow(reg,h)]
  // crow = (reg&3) + 8*(reg>>2) + 4*h
  const float sscale = 1.0f / (FSCALE * FSCALE * 2.0f);   // includes /TAU
  const int r0 = R0 + l31, r1 = R0 + 32 + l31;
  const ulonglong2 rb0 = bits[r0];
  const ulonglong2 rb1 = bits[r1];
  const ulonglong2 cb0 = bits[C0 + l31];
  const ulonglong2 cb1 = bits[C0 + 32 + l31];

  float rs0 = 0.f, ss0 = 0.f, cs0 = 0.f;
  float rs1 = 0.f, ss1 = 0.f, cs1 = 0.f;
#pragma unroll
  for (int reg = 0; reg < 16; ++reg) {
    const int crow = (reg & 3) + 8 * (reg >> 2) + 4 * h;
    const ulonglong2 cq0 = shfl_bits(cb0, crow);   // col C0 + crow
    const ulonglong2 cq1 = shfl_bits(cb1, crow);   // col C0 + 32 + crow
    const bool dg = samegrp && (crow == l31);
    float v00 = acc00[reg] * sscale;  // (r0, C0+crow)      diag candidate
    float v01 = acc01[reg] * sscale;  // (r1, C0+crow)
    float v10 = acc10[reg] * sscale;  // (r0, C0+32+crow)
    float v11 = acc11[reg] * sscale;  // (r1, C0+32+crow)   diag candidate
    float e00 = __expf(v00), e01 = __expf(v01);
    float e10 = __expf(v10), e11 = __expf(v11);
    float o00 = ovl(rb0, cq0) ? 1.f : 0.f;
    float o01 = ovl(rb1, cq0) ? 1.f : 0.f;
    float o10 = ovl(rb0, cq1) ? 1.f : 0.f;
    float o11 = ovl(rb1, cq1) ? 1.f : 0.f;
    if (!dg) {
      rs0 += e00; ss0 = fmaf(o00, v00, ss0); cs0 += o00;
      rs1 += e11; ss1 = fmaf(o11, v11, ss1); cs1 += o11;
    }
    rs0 += e10; ss0 = fmaf(o10, v10, ss0); cs0 += o10;
    rs1 += e01; ss1 = fmaf(o01, v01, ss1); cs1 += o01;
  }
  // combine h-halves (same rows, disjoint cols)
  rs0 += __shfl_xor(rs0, 32, 64); ss0 += __shfl_xor(ss0, 32, 64);
  cs0 += __shfl_xor(cs0, 32, 64);
  rs1 += __shfl_xor(rs1, 32, 64); ss1 += __shfl_xor(ss1, 32, 64);
  cs1 += __shfl_xor(cs1, 32, 64);

  // combine the two wj waves (same rows) via LDS, then one atomic set per row
  __shared__ float red[2][6][32];
  __syncthreads();                       // loop's LDS traffic fully retired
  if (wj == 1 && lane < 32) {
    red[wi][0][lane] = rs0; red[wi][1][lane] = ss0; red[wi][2][lane] = cs0;
    red[wi][3][lane] = rs1; red[wi][4][lane] = ss1; red[wi][5][lane] = cs1;
  }
  __syncthreads();
  if (wj == 0 && lane < 32) {
    rs0 += red[wi][0][lane]; ss0 += red[wi][1][lane]; cs0 += red[wi][2][lane];
    rs1 += red[wi][3][lane]; ss1 += red[wi][4][lane]; cs1 += red[wi][5][lane];
    atomicAdd(R + r0, rs0); atomicAdd(S + r0, ss0); atomicAdd(Cc + r0, cs0);
    atomicAdd(R + r1, rs1); atomicAdd(S + r1, ss1); atomicAdd(Cc + r1, cs1);
  }
}

__global__ __launch_bounds__(1024) void finalize_kernel(
    const float* __restrict__ R, const float* __restrict__ S,
    const float* __restrict__ Cc, const float* __restrict__ lm,
    float* __restrict__ out) {
  int tid = threadIdx.x;
  float s1 = 0.f, s2 = 0.f, slm = 0.f;
  for (int i = tid; i < NN; i += 1024) {
    float r = R[i], s = S[i], c = Cc[i], l = lm[i];
    float logR = __logf(r);
    float lp1 = (c > 0.f) ? (s - c * logR) / c : 0.f;
    // logits_max = sims_ii = 0.5 exactly (normalized rows, row max by C-S)
    float lp2 = (c == 0.f) ? (0.5f - logR) : 0.f;
    s1 += lp1 * l; s2 += lp2; slm += l;
  }
#pragma unroll
  for (int d = 1; d < 64; d <<= 1) {
    s1 += __shfl_xor(s1, d, 64);
    s2 += __shfl_xor(s2, d, 64);
    slm += __shfl_xor(slm, d, 64);
  }
  __shared__ float w1[16], w2[16], w3[16];
  int w = tid >> 6;
  if ((tid & 63) == 0) { w1[w] = s1; w2[w] = s2; w3[w] = slm; }
  __syncthreads();
  if (tid == 0) {
    float a = 0.f, b = 0.f, c2 = 0.f;
    for (int q = 0; q < 16; ++q) { a += w1[q]; b += w2[q]; c2 += w3[q]; }
    const float inv = 1.0f / (float)NN;
    out[0] = -2.0f * (a * inv + b * c2 * inv * inv);
  }
}

extern "C" void kernel_launch(void* const* d_in, const int* in_sizes, int n_in,
                              void* d_out, int out_size, void* d_ws, size_t ws_size,
                              hipStream_t stream) {
  const float* F = (const float*)d_in[0];
  const int* labels = (const int*)d_in[1];
  float* out = (float*)d_out;
  char* ws = (char*)d_ws;

  char* Ft = ws;
  float* R = (float*)(ws + OFF_R);
  float* S = (float*)(ws + OFF_S);
  float* Cc = (float*)(ws + OFF_C);
  ulonglong2* bits = (ulonglong2*)(ws + OFF_BITS);
  float* lm = (float*)(ws + OFF_LM);

  prep_bits_kernel<<<NN / 4, 256, 0, stream>>>(labels, bits, lm, R, S, Cc);
  convert_kernel<<<(NN * 96) / 256, 256, 0, stream>>>(F, Ft);
  main_kernel<<<1024, 256, 0, stream>>>(Ft, bits, R, S, Cc);
  finalize_kernel<<<1, 1024, 0, stream>>>(R, S, Cc, lm, out);
}